// Round 6
// baseline (442.676 us; speedup 1.0000x reference)
//
#include <hip/hip_runtime.h>

typedef unsigned short u16;
typedef unsigned int   u32;
typedef __bf16 bf16x8 __attribute__((ext_vector_type(8)));
typedef u16    u16x8  __attribute__((ext_vector_type(8)));
typedef float  f32x4  __attribute__((ext_vector_type(4)));

#define DI static __device__ __forceinline__

DI float b2f(u16 u){ union { u32 i; float f; } c; c.i = ((u32)u) << 16; return c.f; }
DI u16 f2b(float f){ return __builtin_bit_cast(u16, (__bf16)f); }   // HW RNE cvt
DI float eluf(float x){ return x > 0.f ? x : (__expf(x) - 1.f); }
DI float sigf(float x){ return 1.f / (1.f + __expf(-x)); }
DI f32x4 mfma16(bf16x8 a, bf16x8 b, f32x4 c){
  return __builtin_amdgcn_mfma_f32_16x16x32_bf16(a, b, c, 0, 0, 0);
}
DI bf16x8 ldb(const u16* p){ return *(const bf16x8*)p; }

// ---------------------------------------------------------------------------
// k_pack (unchanged from round 5): blocks 0..1023 pack x; 1024..2439 weights.
// ---------------------------------------------------------------------------
__global__ __launch_bounds__(256) void k_pack(
    const float* __restrict__ x,
    const float* __restrict__ wfc1, const float* __restrict__ wskip,
    const float* __restrict__ vfc1, const float* __restrict__ vfc2,
    const float* __restrict__ vgate, const float* __restrict__ vskip,
    u16* __restrict__ pX, u16* __restrict__ pW1, u16* __restrict__ pF1,
    u16* __restrict__ pSk, u16* __restrict__ pF2, u16* __restrict__ pGa)
{
  __shared__ u16 sX[16 * 1032];
  const int t = threadIdx.x;
  if (blockIdx.x < 1024){
    const int rb = blockIdx.x;
    const float* xp = x + (size_t)rb * 16384;
    #pragma unroll
    for (int it = 0; it < 16; it++){
      float4 v4 = *(const float4*)&xp[it * 1024 + t * 4];
      u16 t0 = f2b(v4.x), t1 = f2b(v4.y), t2 = f2b(v4.z), t3 = f2b(v4.w);
      uint2 pk; pk.x = (u32)t0 | ((u32)t1 << 16); pk.y = (u32)t2 | ((u32)t3 << 16);
      *(uint2*)&sX[it * 1032 + t * 4] = pk;
    }
    __syncthreads();
    u16* dst = pX + (size_t)rb * 16384;
    #pragma unroll
    for (int u = 0; u < 8; u++){
      int c = u * 256 + t;
      int kc = c >> 6, lane = c & 63, ln = lane & 15, q = lane >> 4;
      u16x8 v = *(const u16x8*)&sX[ln * 1032 + kc * 32 + q * 8];
      *(uint4*)&dst[kc * 512 + lane * 8] = __builtin_bit_cast(uint4, v);
    }
    return;
  }
  const int g = (blockIdx.x - 1024) * 256 + t;
  float v8[8];
  u16* dst;
  if (g < 34816){                 // pW1: nb 0..16, kc 0..31 (K=1024)
    int idx = g, lane = idx & 63, kc = (idx >> 6) & 31, nb = idx >> 11;
    int ln = lane & 15, q = lane >> 4;
    #pragma unroll
    for (int j = 0; j < 8; j++){
      int k = kc * 32 + q * 8 + j;
      v8[j] = (nb < 16) ? wfc1[(size_t)k * 256 + nb * 16 + ln]
                        : wskip[(size_t)k * 16 + ln];
    }
    dst = pW1 + (size_t)idx * 8;
  } else if (g < 67584){          // pF1
    int idx = g - 34816, lane = idx & 63, kc = (idx >> 6) & 1, nb = (idx >> 7) & 15, v = idx >> 11;
    int ln = lane & 15, q = lane >> 4;
    #pragma unroll
    for (int j = 0; j < 8; j++){
      int k = kc * 32 + q * 8 + j;
      v8[j] = vfc1[((size_t)v * 64 + k) * 256 + nb * 16 + ln];
    }
    dst = pF1 + (size_t)idx * 8;
  } else if (g < 100352){         // pSk
    int idx = g - 67584, lane = idx & 63, kc = (idx >> 6) & 1, nb = (idx >> 7) & 15, v = idx >> 11;
    int ln = lane & 15, q = lane >> 4;
    #pragma unroll
    for (int j = 0; j < 8; j++){
      int k = kc * 32 + q * 8 + j;
      v8[j] = vskip[((size_t)v * 64 + k) * 256 + nb * 16 + ln];
    }
    dst = pSk + (size_t)idx * 8;
  } else if (g < 231424){         // pF2
    int idx = g - 100352, lane = idx & 63, kc = (idx >> 6) & 7, nb = (idx >> 9) & 15, v = idx >> 13;
    int ln = lane & 15, q = lane >> 4;
    #pragma unroll
    for (int j = 0; j < 8; j++){
      int k = kc * 32 + q * 8 + j;
      v8[j] = vfc2[((size_t)v * 256 + k) * 256 + nb * 16 + ln];
    }
    dst = pF2 + (size_t)idx * 8;
  } else {                        // pGa
    int idx = g - 231424, lane = idx & 63, kc = (idx >> 6) & 7, nb = (idx >> 9) & 15, v = idx >> 13;
    int ln = lane & 15, q = lane >> 4;
    #pragma unroll
    for (int j = 0; j < 8; j++){
      int k = kc * 32 + q * 8 + j;
      v8[j] = vgate[((size_t)v * 256 + k) * 256 + nb * 16 + ln];
    }
    dst = pGa + (size_t)idx * 8;
  }
  u16x8 tv;
  #pragma unroll
  for (int j = 0; j < 8; j++) tv[j] = f2b(v8[j]);
  *(uint4*)dst = __builtin_bit_cast(uint4, tv);
}

// ---------------------------------------------------------------------------
// Pipeline helper blocks (forceinline; fixed buffer pointers at each call
// site -> no runtime-indexed arrays, no scratch).
// ---------------------------------------------------------------------------

// fc2(t): yacc = h_rd @ W2v(t); save fp32 y in ysW; write bf16 y to y_wr.
DI void fc2y(int t, int lane, int ln, int q, int nb0,
             const u16* __restrict__ pF2, const float* __restrict__ b2,
             const u16* h_rd, u16* y_wr, f32x4 (&ysW)[2][2])
{
  f32x4 yacc[2][2];
  #pragma unroll
  for (int mb = 0; mb < 2; mb++)
    #pragma unroll
    for (int i = 0; i < 2; i++){ yacc[mb][i][0]=0.f; yacc[mb][i][1]=0.f; yacc[mb][i][2]=0.f; yacc[mb][i][3]=0.f; }
  #pragma unroll
  for (int kc = 0; kc < 8; kc++){
    bf16x8 B0 = ldb(&pF2[(size_t)((t * 16 + nb0) * 8 + kc) * 512 + lane * 8]);
    bf16x8 B1 = ldb(&pF2[(size_t)((t * 16 + nb0 + 1) * 8 + kc) * 512 + lane * 8]);
    #pragma unroll
    for (int mb = 0; mb < 2; mb++){
      bf16x8 ah = *(const bf16x8*)&h_rd[(mb * 16 + ln) * 264 + kc * 32 + q * 8];
      yacc[mb][0] = mfma16(ah, B0, yacc[mb][0]);
      yacc[mb][1] = mfma16(ah, B1, yacc[mb][1]);
    }
  }
  #pragma unroll
  for (int i = 0; i < 2; i++){
    int col = (nb0 + i) * 16 + ln;
    float vb = b2[t * 256 + col];
    #pragma unroll
    for (int mb = 0; mb < 2; mb++)
      #pragma unroll
      for (int r = 0; r < 4; r++){
        float yy = yacc[mb][i][r] + vb;
        ysW[mb][i][r * 0 + r] = yy;   // plain store
        y_wr[(mb * 16 + q * 4 + r) * 264 + col] = f2b(yy);
      }
  }
}

// gate(vg): gacc = y_rd @ Wg(vg); z += w * sigmoid(gacc+bg) * ysR.
DI void gatez(int vg, int lane, int ln, int q, int nb0,
              const u16* __restrict__ pGa, const float* __restrict__ bg,
              const float* sWt, const u16* y_rd,
              f32x4 (&ysR)[2][2], f32x4 (&z)[2][2])
{
  f32x4 gacc[2][2];
  #pragma unroll
  for (int mb = 0; mb < 2; mb++)
    #pragma unroll
    for (int i = 0; i < 2; i++){ gacc[mb][i][0]=0.f; gacc[mb][i][1]=0.f; gacc[mb][i][2]=0.f; gacc[mb][i][3]=0.f; }
  #pragma unroll
  for (int kc = 0; kc < 8; kc++){
    bf16x8 B0 = ldb(&pGa[(size_t)((vg * 16 + nb0) * 8 + kc) * 512 + lane * 8]);
    bf16x8 B1 = ldb(&pGa[(size_t)((vg * 16 + nb0 + 1) * 8 + kc) * 512 + lane * 8]);
    #pragma unroll
    for (int mb = 0; mb < 2; mb++){
      bf16x8 ah = *(const bf16x8*)&y_rd[(mb * 16 + ln) * 264 + kc * 32 + q * 8];
      gacc[mb][0] = mfma16(ah, B0, gacc[mb][0]);
      gacc[mb][1] = mfma16(ah, B1, gacc[mb][1]);
    }
  }
  float wv[2][4];
  #pragma unroll
  for (int mb = 0; mb < 2; mb++)
    #pragma unroll
    for (int r = 0; r < 4; r++) wv[mb][r] = sWt[(mb * 16 + q * 4 + r) * 16 + vg];
  #pragma unroll
  for (int i = 0; i < 2; i++){
    float vb = bg[vg * 256 + (nb0 + i) * 16 + ln];
    #pragma unroll
    for (int mb = 0; mb < 2; mb++)
      #pragma unroll
      for (int r = 0; r < 4; r++)
        z[mb][i][r] += wv[mb][r] * sigf(gacc[mb][i][r] + vb) * ysR[mb][i][r];
  }
}

// fc1(vn)+skip(vn): h_wr <- elu(Xvn@W1+b1); z += w*(Xvn@Wsk+bs).
DI void fc1skip(int vn, int rb0, int lane, int ln, int q, int nb0,
                const u16* __restrict__ pX, const u16* __restrict__ pF1,
                const u16* __restrict__ pSk,
                const float* __restrict__ b1, const float* __restrict__ bs,
                const float* sWt, u16* h_wr, f32x4 (&z)[2][2])
{
  bf16x8 a0[2], a1[2];
  #pragma unroll
  for (int mb = 0; mb < 2; mb++){
    const u16* xp = &pX[((size_t)(rb0 + mb) * 32 + vn * 2) * 512 + lane * 8];
    a0[mb] = ldb(xp);
    a1[mb] = ldb(xp + 512);
  }
  f32x4 hacc[2][2], racc[2][2];
  #pragma unroll
  for (int mb = 0; mb < 2; mb++)
    #pragma unroll
    for (int i = 0; i < 2; i++){
      hacc[mb][i][0]=0.f; hacc[mb][i][1]=0.f; hacc[mb][i][2]=0.f; hacc[mb][i][3]=0.f;
      racc[mb][i][0]=0.f; racc[mb][i][1]=0.f; racc[mb][i][2]=0.f; racc[mb][i][3]=0.f;
    }
  #pragma unroll
  for (int ks = 0; ks < 2; ks++){
    bf16x8 F0 = ldb(&pF1[(size_t)((vn * 16 + nb0) * 2 + ks) * 512 + lane * 8]);
    bf16x8 F1 = ldb(&pF1[(size_t)((vn * 16 + nb0 + 1) * 2 + ks) * 512 + lane * 8]);
    bf16x8 S0 = ldb(&pSk[(size_t)((vn * 16 + nb0) * 2 + ks) * 512 + lane * 8]);
    bf16x8 S1 = ldb(&pSk[(size_t)((vn * 16 + nb0 + 1) * 2 + ks) * 512 + lane * 8]);
    #pragma unroll
    for (int mb = 0; mb < 2; mb++){
      bf16x8 a = ks ? a1[mb] : a0[mb];
      hacc[mb][0] = mfma16(a, F0, hacc[mb][0]);
      hacc[mb][1] = mfma16(a, F1, hacc[mb][1]);
      racc[mb][0] = mfma16(a, S0, racc[mb][0]);
      racc[mb][1] = mfma16(a, S1, racc[mb][1]);
    }
  }
  #pragma unroll
  for (int i = 0; i < 2; i++){
    int col = (nb0 + i) * 16 + ln;
    float vb = b1[vn * 256 + col];
    #pragma unroll
    for (int mb = 0; mb < 2; mb++)
      #pragma unroll
      for (int r = 0; r < 4; r++)
        h_wr[(mb * 16 + q * 4 + r) * 264 + col] = f2b(eluf(hacc[mb][i][r] + vb));
  }
  float wv[2][4];
  #pragma unroll
  for (int mb = 0; mb < 2; mb++)
    #pragma unroll
    for (int r = 0; r < 4; r++) wv[mb][r] = sWt[(mb * 16 + q * 4 + r) * 16 + vn];
  #pragma unroll
  for (int i = 0; i < 2; i++){
    float vb = bs[vn * 256 + (nb0 + i) * 16 + ln];
    #pragma unroll
    for (int mb = 0; mb < 2; mb++)
      #pragma unroll
      for (int r = 0; r < 4; r++) z[mb][i][r] += wv[mb][r] * (racc[mb][i][r] + vb);
  }
}

// ---------------------------------------------------------------------------
// Fused kernel: weight-GRN prologue (w -> sWt in LDS) + 1-barrier/v pipelined
// per-variable GRN loop.  512 blocks x 32 rows, 512 threads = 8 waves.
// LDS (dynamic, 69632 B): hb0|hb1|yb0|yb1 (4 x 32x264 bf16) + sWt.
// Phase(t) = { fc2(t): hb[t&1]->yb[t&1] | gate(t-1): yb[(t-1)&1] |
//              fc1+skip(t+1): ->hb[(t+1)&1] } -> ONE __syncthreads().
// Same-parity buffer reuse always separated by one barrier (proof in journal).
// ---------------------------------------------------------------------------
__global__ __launch_bounds__(512, 2) void k_fused(
    const u16* __restrict__ pX, const u16* __restrict__ pW1,
    const u16* __restrict__ pF1, const u16* __restrict__ pSk,
    const u16* __restrict__ pF2, const u16* __restrict__ pGa,
    const float* __restrict__ wb1, const float* __restrict__ W2,
    const float* __restrict__ wb2, const float* __restrict__ Wg,
    const float* __restrict__ wbg, const float* __restrict__ wbs,
    const float* __restrict__ b1, const float* __restrict__ b2,
    const float* __restrict__ bg, const float* __restrict__ bs,
    float* __restrict__ out)
{
  extern __shared__ __align__(16) char smem[];
  u16*   hb0 = (u16*)(smem);            // 16896 B each
  u16*   hb1 = (u16*)(smem + 16896);
  u16*   yb0 = (u16*)(smem + 33792);
  u16*   yb1 = (u16*)(smem + 50688);
  float* sWt = (float*)(smem + 67584);  // 2048 B, persists whole kernel
  // prologue-only aliases:
  float* sW2f = (float*)(smem + 33792); // over yb0 (16384 <= 16896)
  float* sR   = (float*)(smem + 16896); // over hb1
  float* sY   = (float*)(smem + 18944);
  float* sWgf = (float*)(smem + 20992);

  const int tid  = threadIdx.x;
  const int lane = tid & 63;
  const int wid  = tid >> 6;
  const int ln   = lane & 15;
  const int q    = lane >> 4;
  const int row0 = blockIdx.x * 32;
  const int rb0  = blockIdx.x * 2;
  const int nb0  = wid * 2;

  // ===================== prologue: weight GRN -> sWt =====================
  {
    const int ncnt = (wid == 7) ? 3 : 2;
    #pragma unroll
    for (int u = 0; u < 2; u++)
      *(float4*)&sW2f[tid * 8 + u * 4] = *(const float4*)&W2[tid * 8 + u * 4];
    if (tid < 256) sWgf[tid] = Wg[tid];

    f32x4 acc[2][3];
    #pragma unroll
    for (int mb = 0; mb < 2; mb++)
      #pragma unroll
      for (int i = 0; i < 3; i++){ acc[mb][i][0]=0.f; acc[mb][i][1]=0.f; acc[mb][i][2]=0.f; acc[mb][i][3]=0.f; }

    for (int kc = 0; kc < 32; kc++){
      bf16x8 a[2];
      #pragma unroll
      for (int mb = 0; mb < 2; mb++)
        a[mb] = ldb(&pX[((size_t)(rb0 + mb) * 32 + kc) * 512 + lane * 8]);
      #pragma unroll
      for (int i = 0; i < 3; i++){
        if (i < ncnt){
          bf16x8 b = ldb(&pW1[(size_t)((nb0 + i) * 32 + kc) * 512 + lane * 8]);
          #pragma unroll
          for (int mb = 0; mb < 2; mb++) acc[mb][i] = mfma16(a[mb], b, acc[mb][i]);
        }
      }
    }

    #pragma unroll
    for (int i = 0; i < 3; i++){
      if (i < ncnt){
        int nb = nb0 + i;
        int col = nb * 16 + ln;
        float vb = (nb < 16) ? wb1[col] : wbs[ln];
        #pragma unroll
        for (int mb = 0; mb < 2; mb++){
          #pragma unroll
          for (int r = 0; r < 4; r++){
            int lr = mb * 16 + q * 4 + r;
            float v = acc[mb][i][r] + vb;
            if (nb < 16) hb0[lr * 264 + col] = f2b(eluf(v));
            else         sR[lr * 16 + ln] = v;
          }
        }
      }
    }
    __syncthreads();

    // y = h @ W2 + b2
    {
      int r = tid >> 4, j = tid & 15;
      float a0 = wb2[j];
      #pragma unroll 4
      for (int kb = 0; kb < 32; kb++){
        u16x8 h8 = *(const u16x8*)&hb0[r * 264 + kb * 8];
        #pragma unroll
        for (int u = 0; u < 8; u++)
          a0 += b2f(h8[u]) * sW2f[(kb * 8 + u) * 16 + j];
      }
      sY[r * 16 + j] = a0;
    }
    __syncthreads();

    // gate = sigmoid(y @ Wg + bg) -> sWt (scratch)
    {
      int r = tid >> 4, j = tid & 15;
      float g0 = wbg[j];
      #pragma unroll
      for (int k = 0; k < 16; k++)
        g0 += sY[r * 16 + k] * sWgf[k * 16 + j];
      sWt[r * 16 + j] = sigf(g0);
    }
    __syncthreads();

    // softmax over 16 -> sWt (thread r owns row r: safe in-place)
    if (tid < 32){
      int r = tid;
      float l[16]; float m = -1e30f;
      #pragma unroll
      for (int j = 0; j < 16; j++){
        float v = sR[r * 16 + j] + sWt[r * 16 + j] * sY[r * 16 + j];
        l[j] = v; m = fmaxf(m, v);
      }
      float s = 0.f;
      #pragma unroll
      for (int j = 0; j < 16; j++){ l[j] = __expf(l[j] - m); s += l[j]; }
      float inv = 1.f / s;
      #pragma unroll
      for (int j = 0; j < 16; j++) sWt[r * 16 + j] = l[j] * inv;
    }
    __syncthreads();
  }

  // ===================== pipelined v-loop, 1 barrier per v =====================
  f32x4 z[2][2], ysE[2][2], ysO[2][2];
  #pragma unroll
  for (int mb = 0; mb < 2; mb++)
    #pragma unroll
    for (int i = 0; i < 2; i++){
      z[mb][i][0]=0.f; z[mb][i][1]=0.f; z[mb][i][2]=0.f; z[mb][i][3]=0.f;
      ysE[mb][i][0]=0.f; ysE[mb][i][1]=0.f; ysE[mb][i][2]=0.f; ysE[mb][i][3]=0.f;
      ysO[mb][i][0]=0.f; ysO[mb][i][1]=0.f; ysO[mb][i][2]=0.f; ysO[mb][i][3]=0.f;
    }

  // pre-phase: fc1+skip(0) -> hb0   (hb0's prologue-h reads finished above)
  fc1skip(0, rb0, lane, ln, q, nb0, pX, pF1, pSk, b1, bs, sWt, hb0, z);
  __syncthreads();

  // phase t=0: fc2(0) hb0->yb0(ysE) ; fc1+skip(1)->hb1   (no gate yet)
  fc2y(0, lane, ln, q, nb0, pF2, b2, hb0, yb0, ysE);
  fc1skip(1, rb0, lane, ln, q, nb0, pX, pF1, pSk, b1, bs, sWt, hb1, z);
  __syncthreads();

  // phases t=1..14 (pairs, compile-time parity)
  #pragma unroll 1
  for (int tp = 0; tp < 7; tp++){
    const int t = 2 * tp + 1;   // odd
    fc2y(t, lane, ln, q, nb0, pF2, b2, hb1, yb1, ysO);
    gatez(t - 1, lane, ln, q, nb0, pGa, bg, sWt, yb0, ysE, z);
    fc1skip(t + 1, rb0, lane, ln, q, nb0, pX, pF1, pSk, b1, bs, sWt, hb0, z);
    __syncthreads();
    fc2y(t + 1, lane, ln, q, nb0, pF2, b2, hb0, yb0, ysE);
    gatez(t, lane, ln, q, nb0, pGa, bg, sWt, yb1, ysO, z);
    fc1skip(t + 2, rb0, lane, ln, q, nb0, pX, pF1, pSk, b1, bs, sWt, hb1, z);
    __syncthreads();
  }

  // phase t=15: fc2(15) hb1->yb1(ysO) ; gate(14) yb0(ysE)  (no next fc1)
  fc2y(15, lane, ln, q, nb0, pF2, b2, hb1, yb1, ysO);
  gatez(14, lane, ln, q, nb0, pGa, bg, sWt, yb0, ysE, z);
  __syncthreads();

  // epilogue: gate(15) yb1(ysO)
  gatez(15, lane, ln, q, nb0, pGa, bg, sWt, yb1, ysO, z);

  // store z -> out (fp32), single writer per element
  #pragma unroll
  for (int i = 0; i < 2; i++){
    int col = (nb0 + i) * 16 + ln;
    #pragma unroll
    for (int mb = 0; mb < 2; mb++)
      #pragma unroll
      for (int r = 0; r < 4; r++)
        out[(size_t)(row0 + mb * 16 + q * 4 + r) * 256 + col] = z[mb][i][r];
  }
}

// ---------------------------------------------------------------------------
extern "C" void kernel_launch(void* const* d_in, const int* in_sizes, int n_in,
                              void* d_out, int out_size, void* d_ws, size_t ws_size,
                              hipStream_t stream)
{
  const float* x     = (const float*)d_in[0];
  const float* wfc1w = (const float*)d_in[1];
  const float* wfc1b = (const float*)d_in[2];
  const float* wfc2w = (const float*)d_in[3];
  const float* wfc2b = (const float*)d_in[4];
  const float* wgw   = (const float*)d_in[5];
  const float* wgb   = (const float*)d_in[6];
  const float* wsw   = (const float*)d_in[7];
  const float* wsb   = (const float*)d_in[8];
  const float* vfc1w = (const float*)d_in[9];
  const float* vfc1b = (const float*)d_in[10];
  const float* vfc2w = (const float*)d_in[11];
  const float* vfc2b = (const float*)d_in[12];
  const float* vgw   = (const float*)d_in[13];
  const float* vgb   = (const float*)d_in[14];
  const float* vsw   = (const float*)d_in[15];
  const float* vsb   = (const float*)d_in[16];

  u16* ws   = (u16*)d_ws;
  u16* pX   = ws;                      // 16777216 u16 (32 MB)
  u16* pW1  = pX + 16777216;           // 278528 u16
  u16* pF1  = pW1 + 278528;            // 262144
  u16* pSk  = pF1 + 262144;            // 262144
  u16* pF2  = pSk + 262144;            // 1048576
  u16* pGa  = pF2 + 1048576;           // 1048576

  k_pack<<<dim3(2440), dim3(256), 0, stream>>>(
      x, wfc1w, wsw, vfc1w, vfc2w, vgw, vsw, pX, pW1, pF1, pSk, pF2, pGa);

  k_fused<<<dim3(512), dim3(512), 69632, stream>>>(
      pX, pW1, pF1, pSk, pF2, pGa,
      wfc1b, wfc2w, wfc2b, wgw, wgb, wsb,
      vfc1b, vfc2b, vgb, vsb, (float*)d_out);
}